// Round 4
// baseline (11103.483 us; speedup 1.0000x reference)
//
#include <hip/hip_runtime.h>

typedef _Float16 v8h __attribute__((ext_vector_type(8)));
typedef float v4f __attribute__((ext_vector_type(4)));

#define NT 512

// ws layout (halves):
//  W1: [p 0..9][ph 0..7][plane hi/lo][512 tid][8]  -> (p*16 + ph*2 + pl)*4096, total 655360
//  W2: [p 0..31][ph2 0..1][plane][512 tid][8]      -> 655360 + (p*4 + ph2*2 + pl)*4096, total 524288
//  att (transposed actions, float) at byte 2359296
static constexpr size_t ATT_BYTES_NEEDED = 2359296ull + 4096ull * 64 * 64 * 4;

#define MFMA16 __builtin_amdgcn_mfma_f32_16x16x32_f16

__device__ __forceinline__ float tanh_fast(float a) {
  float e = __expf(2.0f * a);          // inf for large a -> +/-1 exactly
  return 1.0f - __fdividef(2.0f, e + 1.0f);
}

extern "C" __global__ void conv_w(const float* __restrict__ W1,
                                  const float* __restrict__ W2,
                                  _Float16* __restrict__ ws) {
  int i = blockIdx.x * 256 + threadIdx.x;        // 1179648 total
  int j = i & 7, t = (i >> 3) & 511;
  int lane = t & 63, wave = t >> 6, g = lane >> 4, l15 = lane & 15;
  float v;
  int plane;
  if (i < 655360) {
    plane = (i >> 12) & 1;
    int ph = (i >> 13) & 7, p = i >> 16;
    v = W1[(p * 32 + g * 8 + j) * 1024 + ph * 128 + wave * 16 + l15];
  } else {
    int iq = i - 655360;
    plane = (iq >> 12) & 1;
    int ph2 = (iq >> 13) & 1, p = iq >> 14;
    v = W2[(p * 32 + g * 8 + j) * 256 + ph2 * 128 + wave * 16 + l15];
  }
  _Float16 hh = (_Float16)v;
  ws[i] = plane ? (_Float16)((v - (float)hh) * 2048.f) : hh;
}

extern "C" __global__ void conv_a(const float* __restrict__ actions,
                                  float* __restrict__ att) {
  size_t o = (size_t)blockIdx.x * 256 + threadIdx.x;   // 16777216 total
  int f = (int)(o & 63);
  int b = (int)((o >> 6) & 4095);
  int t = (int)(o >> 18);
  att[o] = actions[((size_t)b * 64 + f) * 64 + t];
}

extern "C" __global__ void __launch_bounds__(NT, 2)
ode_kernel(const float* __restrict__ actions, const float* __restrict__ att,
           const float* __restrict__ y0,
           const float* __restrict__ b1f, const float* __restrict__ b2f,
           const float* __restrict__ dtp, const _Float16* __restrict__ ws,
           float* __restrict__ out)
{
  __shared__ __align__(16) _Float16 xHs[16 * 328], xLs[16 * 328];
  __shared__ __align__(16) _Float16 hHs[16 * 1032], hLs[16 * 1032];

  const int tid  = threadIdx.x;
  const int wave = tid >> 6, lane = tid & 63;
  const int l15  = lane & 15, g = lane >> 4;
  const int nloc = wave * 16 + l15;
  const int b0   = blockIdx.x * 16;
  const float dt = dtp[0];

  const size_t tid8 = (size_t)tid * 8;
  const _Float16* w1 = ws + tid8;              // + site*4096
  const _Float16* w2 = ws + 655360 + tid8;     // + site*4096

  // biases held in registers (column per lane is fixed)
  float b1r[8], b2r0, b2r1;
  #pragma unroll
  for (int ph = 0; ph < 8; ++ph) b1r[ph] = b1f[ph * 128 + nloc];
  b2r0 = b2f[nloc]; b2r1 = b2f[128 + nloc];

  // y state in registers
  float ya[4], yb[4];
  #pragma unroll
  for (int j = 0; j < 4; ++j) {
    int m = g * 4 + j;
    ya[j] = y0[(size_t)(b0 + m) * 256 + nloc];
    yb[j] = y0[(size_t)(b0 + m) * 256 + 128 + nloc];
    out[((size_t)((b0 + m) * 256 + nloc)) * 64] = ya[j];
    out[((size_t)((b0 + m) * 256 + 128 + nloc)) * 64] = yb[j];
  }

  const int xbase = l15 * 328 + g * 8;
  const int hbase = l15 * 1032 + g * 8;

  v8h B1[16], B2f[16];
  // prologue: GEMM1 p=0 fragments for t=0
  #pragma unroll
  for (int f = 0; f < 16; ++f) B1[f] = *(const v8h*)(w1 + f * 4096);

  for (int t = 0; t < 63; ++t) {
    // ---- x-phase: x = [a_t | y] hi/lo planes
    #pragma unroll
    for (int it = 0; it < 2; ++it) {
      int o = tid + NT * it;
      int m = o >> 6, k = o & 63;
      float v = att ? att[((size_t)t * 4096 + b0 + m) * 64 + k]
                    : actions[((size_t)(b0 + m) * 64 + k) * 64 + t];
      _Float16 hh = (_Float16)v;
      xHs[m * 328 + k] = hh;
      xLs[m * 328 + k] = (_Float16)((v - (float)hh) * 2048.f);
    }
    #pragma unroll
    for (int j = 0; j < 4; ++j) {
      int m = g * 4 + j;
      _Float16 h0 = (_Float16)ya[j];
      xHs[m * 328 + 64 + nloc] = h0;
      xLs[m * 328 + 64 + nloc] = (_Float16)((ya[j] - (float)h0) * 2048.f);
      _Float16 h1 = (_Float16)yb[j];
      xHs[m * 328 + 192 + nloc] = h1;
      xLs[m * 328 + 192 + nloc] = (_Float16)((yb[j] - (float)h1) * 2048.f);
    }
    __syncthreads();   // x visible; B1 p=0 loads drained (complete)

    // ======== GEMM1: k-outer (p 0..9), n-inner (ph 0..7), all static ========
    v4f accH[8], accM[8];
    #pragma unroll
    for (int ph = 0; ph < 8; ++ph) {
      accH[ph] = v4f{b1r[ph], b1r[ph], b1r[ph], b1r[ph]};
      accM[ph] = v4f{0.f, 0.f, 0.f, 0.f};
    }
    v8h ah = *(const v8h*)&xHs[xbase];
    v8h al = *(const v8h*)&xLs[xbase];
    #pragma unroll
    for (int p = 0; p < 10; ++p) {
      v8h ah1, al1;
      if (p < 9) {
        ah1 = *(const v8h*)&xHs[xbase + (p + 1) * 32];
        al1 = *(const v8h*)&xLs[xbase + (p + 1) * 32];
      }
      #pragma unroll
      for (int ph = 0; ph < 8; ++ph) {
        v8h bh = B1[ph * 2], bl = B1[ph * 2 + 1];
        if (p < 9) {  // reload this slot for p+1 (consumed a full p from now)
          B1[ph * 2]     = *(const v8h*)(w1 + ((p + 1) * 16 + ph * 2) * 4096);
          B1[ph * 2 + 1] = *(const v8h*)(w1 + ((p + 1) * 16 + ph * 2 + 1) * 4096);
        } else {      // p==9: prefetch GEMM2 p2=0..3 fragments (16 loads)
          B2f[ph * 2]     = *(const v8h*)(w2 + (ph * 2) * 4096);
          B2f[ph * 2 + 1] = *(const v8h*)(w2 + (ph * 2 + 1) * 4096);
        }
        accH[ph] = MFMA16(ah, bh, accH[ph], 0, 0, 0);
        accM[ph] = MFMA16(ah, bl, accM[ph], 0, 0, 0);
        accM[ph] = MFMA16(al, bh, accM[ph], 0, 0, 0);
      }
      ah = ah1; al = al1;
    }
    // h epilogue: tanh + hi/lo split -> LDS
    #pragma unroll
    for (int ph = 0; ph < 8; ++ph) {
      #pragma unroll
      for (int j = 0; j < 4; ++j) {
        float v = accH[ph][j] + accM[ph][j] * (1.f / 2048.f);
        float th = tanh_fast(v);
        _Float16 hh = (_Float16)th;
        int m = g * 4 + j;
        hHs[m * 1032 + ph * 128 + nloc] = hh;
        hLs[m * 1032 + ph * 128 + nloc] = (_Float16)((th - (float)hh) * 2048.f);
      }
    }
    __syncthreads();   // h visible; B2f p2=0..3 drained

    // ======== GEMM2: k-outer (p 0..31), both n-phases live, depth-4 B ========
    v4f c0H = v4f{b2r0, b2r0, b2r0, b2r0}, c0M = v4f{0.f, 0.f, 0.f, 0.f};
    v4f c1H = v4f{b2r1, b2r1, b2r1, b2r1}, c1M = v4f{0.f, 0.f, 0.f, 0.f};
    v8h hh0 = *(const v8h*)&hHs[hbase];
    v8h hl0 = *(const v8h*)&hLs[hbase];
    #pragma unroll
    for (int p = 0; p < 32; ++p) {
      v8h hh1, hl1;
      if (p < 31) {
        hh1 = *(const v8h*)&hHs[hbase + (p + 1) * 32];
        hl1 = *(const v8h*)&hLs[hbase + (p + 1) * 32];
      }
      const int buf = (p & 3) * 4;
      v8h bh0 = B2f[buf], bl0 = B2f[buf + 1], bh1 = B2f[buf + 2], bl1 = B2f[buf + 3];
      if (p < 28) {
        B2f[buf]     = *(const v8h*)(w2 + ((p + 4) * 4 + 0) * 4096);
        B2f[buf + 1] = *(const v8h*)(w2 + ((p + 4) * 4 + 1) * 4096);
        B2f[buf + 2] = *(const v8h*)(w2 + ((p + 4) * 4 + 2) * 4096);
        B2f[buf + 3] = *(const v8h*)(w2 + ((p + 4) * 4 + 3) * 4096);
      }
      c0H = MFMA16(hh0, bh0, c0H, 0, 0, 0);
      c0M = MFMA16(hh0, bl0, c0M, 0, 0, 0);
      c0M = MFMA16(hl0, bh0, c0M, 0, 0, 0);
      c1H = MFMA16(hh0, bh1, c1H, 0, 0, 0);
      c1M = MFMA16(hh0, bl1, c1M, 0, 0, 0);
      c1M = MFMA16(hl0, bh1, c1M, 0, 0, 0);
      hh0 = hh1; hl0 = hl1;
    }
    // y epilogue + out stores
    #pragma unroll
    for (int j = 0; j < 4; ++j) {
      int m = g * 4 + j;
      float yn0 = ya[j] + dt * (c0H[j] + c0M[j] * (1.f / 2048.f));
      ya[j] = yn0;
      out[((size_t)((b0 + m) * 256 + nloc)) * 64 + (t + 1)] = yn0;
      float yn1 = yb[j] + dt * (c1H[j] + c1M[j] * (1.f / 2048.f));
      yb[j] = yn1;
      out[((size_t)((b0 + m) * 256 + 128 + nloc)) * 64 + (t + 1)] = yn1;
    }
    // prefetch next step's GEMM1 p=0 fragments (drained by next barrier)
    if (t < 62) {
      #pragma unroll
      for (int f = 0; f < 16; ++f) B1[f] = *(const v8h*)(w1 + f * 4096);
    }
  }
}

extern "C" void kernel_launch(void* const* d_in, const int* in_sizes, int n_in,
                              void* d_out, int out_size, void* d_ws, size_t ws_size,
                              hipStream_t stream) {
  const float* actions = (const float*)d_in[1];
  const float* y0      = (const float*)d_in[2];
  const float* W1      = (const float*)d_in[3];
  const float* b1      = (const float*)d_in[4];
  const float* W2      = (const float*)d_in[5];
  const float* b2      = (const float*)d_in[6];
  const float* dtp     = (const float*)d_in[7];
  float* out = (float*)d_out;
  _Float16* ws = (_Float16*)d_ws;

  const bool use_att = ws_size >= ATT_BYTES_NEEDED;
  float* att = use_att ? (float*)((char*)d_ws + 2359296) : nullptr;

  hipLaunchKernelGGL(conv_w, dim3(4608), dim3(256), 0, stream, W1, W2, ws);
  if (use_att)
    hipLaunchKernelGGL(conv_a, dim3(65536), dim3(256), 0, stream, actions, att);
  hipLaunchKernelGGL(ode_kernel, dim3(256), dim3(NT), 0, stream,
                     actions, att, y0, b1, b2, dtp, ws, out);
}

// Round 5
// 8039.480 us; speedup vs baseline: 1.3811x; 1.3811x over previous
//
#include <hip/hip_runtime.h>

typedef _Float16 v8h __attribute__((ext_vector_type(8)));
typedef float v4f __attribute__((ext_vector_type(4)));

#define NT 512
#define XSTR 344   // x row stride (halves): 688B, 16B-aligned, 2-way banks
#define HSTR 1032  // h row stride (halves): 2064B, 16B-aligned, 2-way banks

// ws layout (halves):
//  W1H [gp=ph*10+p, 0..79][512 tid][8]  at 0        (327680)
//  W1L                                  at 327680
//  W2H [s=p*2+ph2, 0..63][512 tid][8]   at 655360   (262144)
//  W2L                                  at 917504   (total 1179648 = 2.25 MB)
//  att (transposed actions, float)      at byte 2359296
static constexpr size_t ATT_BYTES_NEEDED = 2359296ull + 4096ull * 64 * 64 * 4;

#define MFMA16 __builtin_amdgcn_mfma_f32_16x16x32_f16

__device__ __forceinline__ float tanh_fast(float a) {
  float e = __expf(2.0f * a);          // inf for large a -> +/-1 exactly
  return 1.0f - __fdividef(2.0f, e + 1.0f);
}

extern "C" __global__ void conv_w(const float* __restrict__ W1,
                                  const float* __restrict__ W2,
                                  _Float16* __restrict__ ws) {
  int i = blockIdx.x * 256 + threadIdx.x;        // 1179648 total
  if (i < 327680) {
    int j = i & 7, lane = (i >> 3) & 63, w = (i >> 9) & 7, gp = i >> 12;
    int g = lane >> 4, l15 = lane & 15;
    int ph = gp / 10, p = gp % 10;
    int k = p * 32 + g * 8 + j, col = ph * 128 + w * 16 + l15;
    float v = W1[k * 1024 + col];
    _Float16 hh = (_Float16)v;
    ws[i] = hh;
    ws[327680 + i] = (_Float16)((v - (float)hh) * 2048.f);
  } else {
    int iq = i - 655360;                          // negative for lo-plane range
    if (iq < 0) iq += 327680;                     // not used; guard below instead
    iq = i - 655360;
    if (iq >= 0 && iq < 262144) {
      int j = iq & 7, t = (iq >> 3) & 511, s = iq >> 12;
      int lane = t & 63, wave = t >> 6, g = lane >> 4, l15 = lane & 15;
      int p = s >> 1, ph2 = s & 1;
      int k = p * 32 + g * 8 + j, col = ph2 * 128 + wave * 16 + l15;
      float v = W2[k * 256 + col];
      _Float16 hh = (_Float16)v;
      ws[655360 + iq] = hh;
      ws[917504 + iq] = (_Float16)((v - (float)hh) * 2048.f);
    }
  }
}

extern "C" __global__ void conv_a(const float* __restrict__ actions,
                                  float* __restrict__ att) {
  size_t o = (size_t)blockIdx.x * 256 + threadIdx.x;   // 16777216 total
  int f = (int)(o & 63);
  int b = (int)((o >> 6) & 4095);
  int t = (int)(o >> 18);
  att[o] = actions[((size_t)b * 64 + f) * 64 + t];
}

extern "C" __global__ void __launch_bounds__(NT, 2)
ode_kernel(const float* __restrict__ actions, const float* __restrict__ att,
           const float* __restrict__ y0,
           const float* __restrict__ b1f, const float* __restrict__ b2f,
           const float* __restrict__ dtp, const _Float16* __restrict__ ws,
           float* __restrict__ out)
{
  __shared__ __align__(16) _Float16 xHs[16 * XSTR], xLs[16 * XSTR];
  __shared__ __align__(16) _Float16 hHs[16 * HSTR], hLs[16 * HSTR];
  __shared__ float b1s[1024];

  const int tid  = threadIdx.x;
  const int lane = tid & 63;
  const int l15  = lane & 15, g = lane >> 4;
  const int nloc = (tid >> 6) * 16 + l15;
  const int b0   = blockIdx.x * 16;
  const float dt = dtp[0];

  const size_t tid8 = (size_t)tid * 8;
  const _Float16* w1h = ws + tid8;              // + gp*4096
  const _Float16* w1l = ws + 327680 + tid8;
  const _Float16* w2h = ws + 655360 + tid8;     // + s*4096
  const _Float16* w2l = ws + 917504 + tid8;

  for (int i = tid; i < 1024; i += NT) b1s[i] = b1f[i];
  const float b2r0 = b2f[nloc], b2r1 = b2f[128 + nloc];

  // y state in registers
  float ya[4], yb[4];
  #pragma unroll
  for (int j = 0; j < 4; ++j) {
    int m = g * 4 + j;
    ya[j] = y0[(size_t)(b0 + m) * 256 + nloc];
    yb[j] = y0[(size_t)(b0 + m) * 256 + 128 + nloc];
    out[((size_t)((b0 + m) * 256 + nloc)) * 64] = ya[j];
    out[((size_t)((b0 + m) * 256 + 128 + nloc)) * 64] = yb[j];
  }

  const int xbase = l15 * XSTR + g * 8;
  const int hbase = l15 * HSTR + g * 8;

  v8h B1h[10], B1l[10];      // depth-10 circular (one ph period)
  v8h B2h[2][4], B2l[2][4];  // depth-4 per n-phase

  // prologue: ph=0 sites for t=0
  #pragma unroll
  for (int p = 0; p < 10; ++p) {
    B1h[p] = *(const v8h*)(w1h + p * 4096);
    B1l[p] = *(const v8h*)(w1l + p * 4096);
  }

  #pragma unroll 1
  for (int t = 0; t < 63; ++t) {
    // ---- x-phase: x = [a_t | y] hi/lo planes
    #pragma unroll
    for (int it = 0; it < 2; ++it) {
      int o = tid + NT * it;
      int m = o >> 6, k = o & 63;
      float v = att ? att[((size_t)t * 4096 + b0 + m) * 64 + k]
                    : actions[((size_t)(b0 + m) * 64 + k) * 64 + t];
      _Float16 hh = (_Float16)v;
      xHs[m * XSTR + k] = hh;
      xLs[m * XSTR + k] = (_Float16)((v - (float)hh) * 2048.f);
    }
    #pragma unroll
    for (int j = 0; j < 4; ++j) {
      int m = g * 4 + j;
      _Float16 h0 = (_Float16)ya[j];
      xHs[m * XSTR + 64 + nloc] = h0;
      xLs[m * XSTR + 64 + nloc] = (_Float16)((ya[j] - (float)h0) * 2048.f);
      _Float16 h1 = (_Float16)yb[j];
      xHs[m * XSTR + 192 + nloc] = h1;
      xLs[m * XSTR + 192 + nloc] = (_Float16)((yb[j] - (float)h1) * 2048.f);
    }
    __syncthreads();   // x visible; B1 ph=0 loads drained

    // ======== GEMM1: ph real-outer, p unrolled-inner, circular depth-10 ====
    const _Float16* w1hp = w1h;   // current ph base
    const _Float16* w1lp = w1l;
    #pragma unroll 1
    for (int ph = 0; ph < 8; ++ph) {
      const float bb = b1s[ph * 128 + nloc];
      v4f accH = v4f{bb, bb, bb, bb};
      v4f accM = v4f{0.f, 0.f, 0.f, 0.f};
      v8h xch = *(const v8h*)&xHs[xbase];
      v8h xcl = *(const v8h*)&xLs[xbase];
      #pragma unroll
      for (int p = 0; p < 10; ++p) {
        v8h bh = B1h[p], bl = B1l[p];
        if (ph < 7) {   // reload this slot for ph+1 (consumed 10 bodies later)
          B1h[p] = *(const v8h*)(w1hp + 40960 + p * 4096);
          B1l[p] = *(const v8h*)(w1lp + 40960 + p * 4096);
        } else if (p < 8) {   // ph==7: spread GEMM2 prologue, sites s=p
          B2h[p & 1][p >> 1] = *(const v8h*)(w2h + p * 4096);
          B2l[p & 1][p >> 1] = *(const v8h*)(w2l + p * 4096);
        }
        v8h xnh, xnl;
        if (p < 9) {
          xnh = *(const v8h*)&xHs[xbase + (p + 1) * 32];
          xnl = *(const v8h*)&xLs[xbase + (p + 1) * 32];
        }
        accH = MFMA16(xch, bh, accH, 0, 0, 0);
        accM = MFMA16(xch, bl, accM, 0, 0, 0);
        accM = MFMA16(xcl, bh, accM, 0, 0, 0);
        xch = xnh; xcl = xnl;
      }
      // epilogue: tanh + hi/lo split -> h planes
      #pragma unroll
      for (int j = 0; j < 4; ++j) {
        float v = accH[j] + accM[j] * (1.f / 2048.f);
        float th = tanh_fast(v);
        _Float16 hh = (_Float16)th;
        int m = g * 4 + j;
        hHs[m * HSTR + ph * 128 + nloc] = hh;
        hLs[m * HSTR + ph * 128 + nloc] = (_Float16)((th - (float)hh) * 2048.f);
      }
      w1hp += 40960; w1lp += 40960;
    }
    __syncthreads();   // h visible; B2 sites 0..7 drained

    // ======== GEMM2: p unrolled, both n-phases live, circular depth-4 ======
    v4f c0H = v4f{b2r0, b2r0, b2r0, b2r0}, c0M = v4f{0.f, 0.f, 0.f, 0.f};
    v4f c1H = v4f{b2r1, b2r1, b2r1, b2r1}, c1M = v4f{0.f, 0.f, 0.f, 0.f};
    v8h hh0 = *(const v8h*)&hHs[hbase];
    v8h hl0 = *(const v8h*)&hLs[hbase];
    #pragma unroll
    for (int p = 0; p < 32; ++p) {
      v8h bh0 = B2h[0][p & 3], bl0 = B2l[0][p & 3];
      v8h bh1 = B2h[1][p & 3], bl1 = B2l[1][p & 3];
      if (p < 28) {   // reload slots for p+4 (sites 2(p+4), 2(p+4)+1)
        B2h[0][p & 3] = *(const v8h*)(w2h + (size_t)(2 * (p + 4)) * 4096);
        B2l[0][p & 3] = *(const v8h*)(w2l + (size_t)(2 * (p + 4)) * 4096);
        B2h[1][p & 3] = *(const v8h*)(w2h + (size_t)(2 * (p + 4) + 1) * 4096);
        B2l[1][p & 3] = *(const v8h*)(w2l + (size_t)(2 * (p + 4) + 1) * 4096);
      }
      v8h hh1, hl1;
      if (p < 31) {
        hh1 = *(const v8h*)&hHs[hbase + (p + 1) * 32];
        hl1 = *(const v8h*)&hLs[hbase + (p + 1) * 32];
      }
      c0H = MFMA16(hh0, bh0, c0H, 0, 0, 0);
      c0M = MFMA16(hh0, bl0, c0M, 0, 0, 0);
      c0M = MFMA16(hl0, bh0, c0M, 0, 0, 0);
      c1H = MFMA16(hh0, bh1, c1H, 0, 0, 0);
      c1M = MFMA16(hh0, bl1, c1M, 0, 0, 0);
      c1M = MFMA16(hl0, bh1, c1M, 0, 0, 0);
      hh0 = hh1; hl0 = hl1;
    }
    // y epilogue + out stores
    #pragma unroll
    for (int j = 0; j < 4; ++j) {
      int m = g * 4 + j;
      float yn0 = ya[j] + dt * (c0H[j] + c0M[j] * (1.f / 2048.f));
      ya[j] = yn0;
      out[((size_t)((b0 + m) * 256 + nloc)) * 64 + (t + 1)] = yn0;
      float yn1 = yb[j] + dt * (c1H[j] + c1M[j] * (1.f / 2048.f));
      yb[j] = yn1;
      out[((size_t)((b0 + m) * 256 + 128 + nloc)) * 64 + (t + 1)] = yn1;
    }
    // prefetch next step's ph=0 sites (drained by next x-barrier)
    if (t < 62) {
      #pragma unroll
      for (int p = 0; p < 10; ++p) {
        B1h[p] = *(const v8h*)(w1h + p * 4096);
        B1l[p] = *(const v8h*)(w1l + p * 4096);
      }
    }
  }
}

extern "C" void kernel_launch(void* const* d_in, const int* in_sizes, int n_in,
                              void* d_out, int out_size, void* d_ws, size_t ws_size,
                              hipStream_t stream) {
  const float* actions = (const float*)d_in[1];
  const float* y0      = (const float*)d_in[2];
  const float* W1      = (const float*)d_in[3];
  const float* b1      = (const float*)d_in[4];
  const float* W2      = (const float*)d_in[5];
  const float* b2      = (const float*)d_in[6];
  const float* dtp     = (const float*)d_in[7];
  float* out = (float*)d_out;
  _Float16* ws = (_Float16*)d_ws;

  const bool use_att = ws_size >= ATT_BYTES_NEEDED;
  float* att = use_att ? (float*)((char*)d_ws + 2359296) : nullptr;

  hipLaunchKernelGGL(conv_w, dim3(4608), dim3(256), 0, stream, W1, W2, ws);
  if (use_att)
    hipLaunchKernelGGL(conv_a, dim3(65536), dim3(256), 0, stream, actions, att);
  hipLaunchKernelGGL(ode_kernel, dim3(256), dim3(NT), 0, stream,
                     actions, att, y0, b1, b2, dtp, ws, out);
}

// Round 6
// 3258.028 us; speedup vs baseline: 3.4080x; 2.4676x over previous
//
#include <hip/hip_runtime.h>

typedef _Float16 v8h __attribute__((ext_vector_type(8)));
typedef float v4f __attribute__((ext_vector_type(4)));

#define NT 512
#define XSTR 344   // x row stride (halves): 688B, 16B-aligned
#define HSTR 1032  // h row stride (halves): 2064B, 16B-aligned

// ws layout (halves):
//  W1H [gp=ph*10+p, 0..79][512 tid][8]  at 0        (327680)
//  W1L                                  at 327680
//  W2H [s=p*2+ph2, 0..63][512 tid][8]   at 655360   (262144)
//  W2L                                  at 917504   (total 1179648 = 2.25 MB)
//  att (transposed actions, float)      at byte 2359296
static constexpr size_t ATT_BYTES_NEEDED = 2359296ull + 4096ull * 64 * 64 * 4;

#define MFMA16 __builtin_amdgcn_mfma_f32_16x16x32_f16

__device__ __forceinline__ float tanh_fast(float a) {
  float e = __expf(2.0f * a);          // inf for large a -> +/-1 exactly
  return 1.0f - __fdividef(2.0f, e + 1.0f);
}

extern "C" __global__ void conv_w(const float* __restrict__ W1,
                                  const float* __restrict__ W2,
                                  _Float16* __restrict__ ws) {
  int i = blockIdx.x * 256 + threadIdx.x;        // 917504 total
  if (i < 327680) {
    int j = i & 7, lane = (i >> 3) & 63, w = (i >> 9) & 7, gp = i >> 12;
    int g = lane >> 4, l15 = lane & 15;
    int ph = gp / 10, p = gp % 10;
    float v = W1[(p * 32 + g * 8 + j) * 1024 + ph * 128 + w * 16 + l15];
    _Float16 hh = (_Float16)v;
    ws[i] = hh;
    ws[327680 + i] = (_Float16)((v - (float)hh) * 2048.f);
  } else {
    int iq = i - 655360;
    if (iq >= 0 && iq < 262144) {
      int j = iq & 7, t = (iq >> 3) & 511, s = iq >> 12;
      int lane = t & 63, wave = t >> 6, g = lane >> 4, l15 = lane & 15;
      int p = s >> 1, ph2 = s & 1;
      float v = W2[(p * 32 + g * 8 + j) * 256 + ph2 * 128 + wave * 16 + l15];
      _Float16 hh = (_Float16)v;
      ws[655360 + iq] = hh;
      ws[917504 + iq] = (_Float16)((v - (float)hh) * 2048.f);
    }
  }
}

extern "C" __global__ void conv_a(const float* __restrict__ actions,
                                  float* __restrict__ att) {
  size_t o = (size_t)blockIdx.x * 256 + threadIdx.x;   // 16777216 total
  int f = (int)(o & 63);
  int b = (int)((o >> 6) & 4095);
  int t = (int)(o >> 18);
  att[o] = actions[((size_t)b * 64 + f) * 64 + t];
}

extern "C" __global__ void __launch_bounds__(NT, 1)
ode_kernel(const float* __restrict__ actions, const float* __restrict__ att,
           const float* __restrict__ y0,
           const float* __restrict__ b1f, const float* __restrict__ b2f,
           const float* __restrict__ dtp, const _Float16* __restrict__ ws,
           float* __restrict__ out)
{
  __shared__ __align__(16) _Float16 xHs[16 * XSTR], xLs[16 * XSTR];
  __shared__ __align__(16) _Float16 hHs[16 * HSTR], hLs[16 * HSTR];
  __shared__ float b1s[1024];

  const int tid  = threadIdx.x;
  const int lane = tid & 63;
  const int l15  = lane & 15, g = lane >> 4;
  const int nloc = (tid >> 6) * 16 + l15;
  const int b0   = blockIdx.x * 16;
  const float dt = dtp[0];

  const size_t tid8 = (size_t)tid * 8;
  const _Float16* w1h = ws + tid8;              // + gp*4096
  const _Float16* w1l = ws + 327680 + tid8;
  const _Float16* w2h = ws + 655360 + tid8;     // + s*4096
  const _Float16* w2l = ws + 917504 + tid8;

  for (int i = tid; i < 1024; i += NT) b1s[i] = b1f[i];
  const float b2r0 = b2f[nloc], b2r1 = b2f[128 + nloc];

  // y state in registers
  float ya[4], yb[4];
  #pragma unroll
  for (int j = 0; j < 4; ++j) {
    int m = g * 4 + j;
    ya[j] = y0[(size_t)(b0 + m) * 256 + nloc];
    yb[j] = y0[(size_t)(b0 + m) * 256 + 128 + nloc];
    out[((size_t)((b0 + m) * 256 + nloc)) * 64] = ya[j];
    out[((size_t)((b0 + m) * 256 + 128 + nloc)) * 64] = yb[j];
  }

  const int xbase = l15 * XSTR + g * 8;
  const int hbase = l15 * HSTR + g * 8;

  v8h B1h[10], B1l[10];      // depth-10 circular (one ph period)
  v8h B2h[2][4], B2l[2][4];  // depth-4 per n-phase

  // prologue: ph=0 sites for t=0
  #pragma unroll
  for (int p = 0; p < 10; ++p) {
    B1h[p] = *(const v8h*)(w1h + p * 4096);
    B1l[p] = *(const v8h*)(w1l + p * 4096);
  }

  #pragma unroll 1
  for (int t = 0; t < 63; ++t) {
    // ---- x-phase: x = [a_t | y] hi/lo planes
    #pragma unroll
    for (int it = 0; it < 2; ++it) {
      int o = tid + NT * it;
      int m = o >> 6, k = o & 63;
      float v = att ? att[((size_t)t * 4096 + b0 + m) * 64 + k]
                    : actions[((size_t)(b0 + m) * 64 + k) * 64 + t];
      _Float16 hh = (_Float16)v;
      xHs[m * XSTR + k] = hh;
      xLs[m * XSTR + k] = (_Float16)((v - (float)hh) * 2048.f);
    }
    #pragma unroll
    for (int j = 0; j < 4; ++j) {
      int m = g * 4 + j;
      _Float16 h0 = (_Float16)ya[j];
      xHs[m * XSTR + 64 + nloc] = h0;
      xLs[m * XSTR + 64 + nloc] = (_Float16)((ya[j] - (float)h0) * 2048.f);
      _Float16 h1 = (_Float16)yb[j];
      xHs[m * XSTR + 192 + nloc] = h1;
      xLs[m * XSTR + 192 + nloc] = (_Float16)((yb[j] - (float)h1) * 2048.f);
    }
    __syncthreads();   // x visible; B1 ph=0 loads drained

    // ======== GEMM1: ph real-outer, p static-inner, circular depth-10 =====
    const _Float16* w1hp = w1h;
    const _Float16* w1lp = w1l;
    #pragma unroll 1
    for (int ph = 0; ph < 8; ++ph) {
      const float bb = b1s[ph * 128 + nloc];
      v4f accH = v4f{bb, bb, bb, bb};
      v4f accM = v4f{0.f, 0.f, 0.f, 0.f};
      v8h xch = *(const v8h*)&xHs[xbase];
      v8h xcl = *(const v8h*)&xLs[xbase];
      #pragma unroll
      for (int p = 0; p < 10; ++p) {
        v8h bh = B1h[p], bl = B1l[p];
        if (ph < 7) {   // reload this slot for ph+1 (consumed 10 bodies later)
          B1h[p] = *(const v8h*)(w1hp + 40960 + p * 4096);
          B1l[p] = *(const v8h*)(w1lp + 40960 + p * 4096);
        } else if (p < 8) {   // ph==7: spread GEMM2 prologue, sites s=p
          B2h[p & 1][p >> 1] = *(const v8h*)(w2h + p * 4096);
          B2l[p & 1][p >> 1] = *(const v8h*)(w2l + p * 4096);
        }
        v8h xnh, xnl;
        if (p < 9) {
          xnh = *(const v8h*)&xHs[xbase + (p + 1) * 32];
          xnl = *(const v8h*)&xLs[xbase + (p + 1) * 32];
        }
        accH = MFMA16(xch, bh, accH, 0, 0, 0);
        accM = MFMA16(xch, bl, accM, 0, 0, 0);
        accM = MFMA16(xcl, bh, accM, 0, 0, 0);
        xch = xnh; xcl = xnl;
      }
      // epilogue: tanh + hi/lo split -> h planes
      #pragma unroll
      for (int j = 0; j < 4; ++j) {
        float v = accH[j] + accM[j] * (1.f / 2048.f);
        float th = tanh_fast(v);
        _Float16 hh = (_Float16)th;
        int m = g * 4 + j;
        hHs[m * HSTR + ph * 128 + nloc] = hh;
        hLs[m * HSTR + ph * 128 + nloc] = (_Float16)((th - (float)hh) * 2048.f);
      }
      w1hp += 40960; w1lp += 40960;
    }
    __syncthreads();   // h visible; B2 sites 0..7 drained

    // ======== GEMM2: po real-outer (8), u static-inner (4), depth-4 =======
    v4f c0H = v4f{b2r0, b2r0, b2r0, b2r0}, c0M = v4f{0.f, 0.f, 0.f, 0.f};
    v4f c1H = v4f{b2r1, b2r1, b2r1, b2r1}, c1M = v4f{0.f, 0.f, 0.f, 0.f};
    v8h hh0 = *(const v8h*)&hHs[hbase];
    v8h hl0 = *(const v8h*)&hLs[hbase];
    #pragma unroll 1
    for (int po = 0; po < 8; ++po) {
      #pragma unroll
      for (int u = 0; u < 4; ++u) {
        const int p = po * 4 + u;
        v8h bh0 = B2h[0][u], bl0 = B2l[0][u];
        v8h bh1 = B2h[1][u], bl1 = B2l[1][u];
        if (po < 7) {   // reload slots for p+4 (sites 2(p+4), 2(p+4)+1)
          B2h[0][u] = *(const v8h*)(w2h + (size_t)(2 * (p + 4)) * 4096);
          B2l[0][u] = *(const v8h*)(w2l + (size_t)(2 * (p + 4)) * 4096);
          B2h[1][u] = *(const v8h*)(w2h + (size_t)(2 * (p + 4) + 1) * 4096);
          B2l[1][u] = *(const v8h*)(w2l + (size_t)(2 * (p + 4) + 1) * 4096);
        }
        v8h hh1, hl1;
        if (p < 31) {
          hh1 = *(const v8h*)&hHs[hbase + (p + 1) * 32];
          hl1 = *(const v8h*)&hLs[hbase + (p + 1) * 32];
        }
        c0H = MFMA16(hh0, bh0, c0H, 0, 0, 0);
        c0M = MFMA16(hh0, bl0, c0M, 0, 0, 0);
        c0M = MFMA16(hl0, bh0, c0M, 0, 0, 0);
        c1H = MFMA16(hh0, bh1, c1H, 0, 0, 0);
        c1M = MFMA16(hh0, bl1, c1M, 0, 0, 0);
        c1M = MFMA16(hl0, bh1, c1M, 0, 0, 0);
        hh0 = hh1; hl0 = hl1;
      }
    }
    // y epilogue + out stores
    #pragma unroll
    for (int j = 0; j < 4; ++j) {
      int m = g * 4 + j;
      float yn0 = ya[j] + dt * (c0H[j] + c0M[j] * (1.f / 2048.f));
      ya[j] = yn0;
      out[((size_t)((b0 + m) * 256 + nloc)) * 64 + (t + 1)] = yn0;
      float yn1 = yb[j] + dt * (c1H[j] + c1M[j] * (1.f / 2048.f));
      yb[j] = yn1;
      out[((size_t)((b0 + m) * 256 + 128 + nloc)) * 64 + (t + 1)] = yn1;
    }
    // prefetch next step's ph=0 sites (drained by next x-barrier)
    if (t < 62) {
      #pragma unroll
      for (int p = 0; p < 10; ++p) {
        B1h[p] = *(const v8h*)(w1h + p * 4096);
        B1l[p] = *(const v8h*)(w1l + p * 4096);
      }
    }
  }
}

extern "C" void kernel_launch(void* const* d_in, const int* in_sizes, int n_in,
                              void* d_out, int out_size, void* d_ws, size_t ws_size,
                              hipStream_t stream) {
  const float* actions = (const float*)d_in[1];
  const float* y0      = (const float*)d_in[2];
  const float* W1      = (const float*)d_in[3];
  const float* b1      = (const float*)d_in[4];
  const float* W2      = (const float*)d_in[5];
  const float* b2      = (const float*)d_in[6];
  const float* dtp     = (const float*)d_in[7];
  float* out = (float*)d_out;
  _Float16* ws = (_Float16*)d_ws;

  const bool use_att = ws_size >= ATT_BYTES_NEEDED;
  float* att = use_att ? (float*)((char*)d_ws + 2359296) : nullptr;

  hipLaunchKernelGGL(conv_w, dim3(3584), dim3(256), 0, stream, W1, W2, ws);
  if (use_att)
    hipLaunchKernelGGL(conv_a, dim3(65536), dim3(256), 0, stream, actions, att);
  hipLaunchKernelGGL(ode_kernel, dim3(256), dim3(NT), 0, stream,
                     actions, att, y0, b1, b2, dtp, ws, out);
}